// Round 2
// baseline (186.712 us; speedup 1.0000x reference)
//
#include <hip/hip_runtime.h>
#include <hip/hip_bf16.h>

// out[i] = sum_{j!=i} relu(Wd_i@x_j + (Ws_i-Wd_i)@x_i + b_i) * x_j + x_i, 3 steps.
// MFMA 16x16x32 f16 with SCALED 2-WAY f16 split: v = h + m*2^-11 (rep err
// ~2^-24, fp32-class: absmax 1.0 == fp32 baseline R1/R7).
// Edge: hh + 2^-11*(hm+mh); Q keeps mm too.
// R8: 512-thread blocks, 8 waves, wave w = receiver w (ONE receiver/wave).
// R9 counters: 64.5us/dispatch, VGPR=48, Occ 36%, Mfma 28%, VALU 43% — still
// latency-bound, no pipe saturated. But VGPR=48 <= 64: the (512,4) bound was
// the only thing capping residency at 2 blocks/CU.
// R10: __launch_bounds__(512,8) -> 8 waves/SIMD = 4 blocks/CU.
//   LDS check: 4 x 38912 = 155.6 KB <= 160 KB. VGPR check: 48 <= 64 cap.
// Spill go/no-go: FETCH/WRITE must stay ~37/37 MB (R4/R6 spills showed 270+).
// LDS: f16 split pair xs[2] (B-frags) + fp32 gating master xg; staged epilogue.

#define NN 8
#define NSTEPS 3
#define BB 4
#define CC 32
#define HWSZ 9216
#define PX 16
#define CPS 40   // f16 row stride (80 B)
#define CPG 36   // f32 row stride (144 B)
#define MSC 2048.0f
#define SINV 4.8828125e-4f   // 2^-11

typedef _Float16 f16x8 __attribute__((ext_vector_type(8)));
typedef _Float16 f16x4 __attribute__((ext_vector_type(4)));
typedef _Float16 f16x2 __attribute__((ext_vector_type(2)));
typedef float    f32x4 __attribute__((ext_vector_type(4)));
typedef float    f32x2 __attribute__((ext_vector_type(2)));

#define MFMA(A, B, C) __builtin_amdgcn_mfma_f32_16x16x32_f16((A), (B), (C), 0, 0, 0)

__device__ __forceinline__ void split2s(float v, _Float16& h, _Float16& m) {
    h = (_Float16)v;
    m = (_Float16)((v - (float)h) * MSC);
}

__global__ __launch_bounds__(512, 8)
void gcn3_f16w(const float* __restrict__ nodes,
               const float* __restrict__ we,
               const float* __restrict__ be,
               float* __restrict__ out) {
    __shared__ _Float16 xs[2][NN][PX][CPS];   // 20480 B
    __shared__ float    xg[NN][PX][CPG];      // 18432 B (total 38912)

    const int tid  = threadIdx.x;
    const int wid  = tid >> 6;     // receiver node i (0..7), one per wave
    const int lane = tid & 63;
    const int col  = lane & 15;    // pixel (B n / C col); A row m
    const int quad = lane >> 4;    // 0..3

    const f32x4 zero4 = {0.f, 0.f, 0.f, 0.f};

    // ---- resident A-frags for ONE receiver: Wd, (Ws-Wd); 2-way scaled split ----
    f16x8 awd[2][2], awsd[2][2];   // [tile][split] = 32 VGPRs
    f32x4 bias[2];
    #pragma unroll
    for (int t = 0; t < 2; ++t) {
        const float* wp = we + (size_t)((wid * CC + 16 * t + col) * (2 * CC)) + quad * 8;
        f32x4 d0 = *(const f32x4*)wp;
        f32x4 d1 = *(const f32x4*)(wp + 4);
        f32x4 s0 = *(const f32x4*)(wp + CC);
        f32x4 s1 = *(const f32x4*)(wp + CC + 4);
        #pragma unroll
        for (int k = 0; k < 8; ++k) {
            float d = (k < 4) ? d0[k & 3] : d1[k & 3];
            float s = (k < 4) ? s0[k & 3] : s1[k & 3];
            _Float16 h, m;
            split2s(d, h, m);
            awd[t][0][k] = h; awd[t][1][k] = m;
            split2s(s - d, h, m);
            awsd[t][0][k] = h; awsd[t][1][k] = m;
        }
        #pragma unroll
        for (int k = 0; k < 4; ++k)
            bias[t][k] = be[wid * CC + 16 * t + quad * 4 + k];
    }

    const int q0  = blockIdx.x * PX;
    const int b   = q0 / HWSZ;
    const int hw0 = q0 - b * HWSZ;

    // ---- stage: 1024 f32x2 units over 512 threads (2 iters) ----
    #pragma unroll
    for (int kk = 0; kk < 2; ++kk) {
        int idx = tid + kk * 512;            // 1024 = 8n * 16c2 * 8p2
        int p2 = (idx & 7) * 2;
        int c2 = ((idx >> 3) & 15) * 2;
        int n  = idx >> 7;
        const float* gp = nodes + (size_t)((n * BB + b) * CC + c2) * HWSZ + hw0 + p2;
        f32x2 v0 = *(const f32x2*)gp;            // channel c2
        f32x2 v1 = *(const f32x2*)(gp + HWSZ);   // channel c2+1
        #pragma unroll
        for (int e = 0; e < 2; ++e) {
            _Float16 h0, m0, h1, m1;
            split2s(v0[e], h0, m0);
            split2s(v1[e], h1, m1);
            *(f16x2*)&xs[0][n][p2 + e][c2] = f16x2{h0, h1};
            *(f16x2*)&xs[1][n][p2 + e][c2] = f16x2{m0, m1};
            *(f32x2*)&xg[n][p2 + e][c2] = f32x2{v0[e], v1[e]};
        }
    }
    __syncthreads();

    f32x4 msg[2];

    #pragma unroll 1
    for (int step = 0; step < NSTEPS; ++step) {
        // ---- Q = (Ws-Wd)_i @ x_i + b : all 4 split products ----
        f32x4 qf[2];
        {
            f16x8 bh = *(const f16x8*)&xs[0][wid][col][quad * 8];
            f16x8 bm = *(const f16x8*)&xs[1][wid][col][quad * 8];
            #pragma unroll
            for (int t = 0; t < 2; ++t) {
                f32x4 q1 = MFMA(awsd[t][0], bh, bias[t]);   // hh (+bias)
                f32x4 q2 = MFMA(awsd[t][0], bm, zero4);     // hm
                q2 = MFMA(awsd[t][1], bh, q2);              // mh
                f32x4 q3 = MFMA(awsd[t][1], bm, zero4);     // mm
                #pragma unroll
                for (int k = 0; k < 4; ++k)
                    qf[t][k] = fmaf(fmaf(q3[k], SINV, q2[k]), SINV, q1[k]);
            }
        }

        #pragma unroll
        for (int t = 0; t < 2; ++t)
            msg[t] = zero4;

        // ---- sender loop: E = Wd x_j + Q (hh, hm, mh kept) ----
        #pragma unroll
        for (int j = 0; j < NN; ++j) {
            f32x4 xgj[2];
            #pragma unroll
            for (int t = 0; t < 2; ++t)
                xgj[t] = *(const f32x4*)&xg[j][col][16 * t + quad * 4];
            if (j == wid) {                  // wave-uniform: residual
                #pragma unroll
                for (int t = 0; t < 2; ++t)
                    #pragma unroll
                    for (int k = 0; k < 4; ++k)
                        msg[t][k] += xgj[t][k];
            } else {
                f16x8 bh = *(const f16x8*)&xs[0][j][col][quad * 8];
                f16x8 bm = *(const f16x8*)&xs[1][j][col][quad * 8];
                #pragma unroll
                for (int t = 0; t < 2; ++t) {
                    f32x4 e1 = MFMA(awd[t][0], bh, qf[t]);   // hh (+Q)
                    f32x4 e2 = MFMA(awd[t][0], bm, zero4);   // hm
                    e2 = MFMA(awd[t][1], bh, e2);            // mh
                    #pragma unroll
                    for (int k = 0; k < 4; ++k) {
                        float g = fmaxf(fmaf(e2[k], SINV, e1[k]), 0.f);
                        msg[t][k] = fmaf(g, xgj[t][k], msg[t][k]);
                    }
                }
            }
        }

        if (step < NSTEPS - 1) {
            __syncthreads();   // all reads of old x done
            #pragma unroll
            for (int t = 0; t < 2; ++t) {
                f16x4 h4, m4;
                #pragma unroll
                for (int k = 0; k < 4; ++k) {
                    _Float16 h, m;
                    split2s(msg[t][k], h, m);
                    h4[k] = h; m4[k] = m;
                }
                *(f16x4*)&xs[0][wid][col][16 * t + quad * 4] = h4;
                *(f16x4*)&xs[1][wid][col][16 * t + quad * 4] = m4;
                *(f32x4*)&xg[wid][col][16 * t + quad * 4] = msg[t];
            }
            __syncthreads();   // new x visible
        }
    }

    // ---- epilogue: stage final msg in LDS, then full-line coalesced stores ----
    __syncthreads();
    #pragma unroll
    for (int t = 0; t < 2; ++t)
        *(f32x4*)&xg[wid][col][16 * t + quad * 4] = msg[t];
    __syncthreads();
    #pragma unroll
    for (int kk = 0; kk < 2; ++kk) {
        int idx = tid + kk * 512;            // 1024 = 8n * 32c * 4p4
        int p4 = (idx & 3) * 4;
        int c  = (idx >> 2) & 31;
        int n  = idx >> 7;
        f32x4 v;
        #pragma unroll
        for (int e = 0; e < 4; ++e) v[e] = xg[n][p4 + e][c];
        *(f32x4*)(out + (size_t)((n * BB + b) * CC + c) * HWSZ + hw0 + p4) = v;
    }
}

extern "C" void kernel_launch(void* const* d_in, const int* in_sizes, int n_in,
                              void* d_out, int out_size, void* d_ws, size_t ws_size,
                              hipStream_t stream) {
    const float* nodes  = (const float*)d_in[0];
    const float* W_edge = (const float*)d_in[1];
    const float* b_edge = (const float*)d_in[2];
    float* outp = (float*)d_out;

    dim3 grid((BB * HWSZ) / PX);   // 2304 blocks of 512
    dim3 block(512);
    gcn3_f16w<<<grid, block, 0, stream>>>(nodes, W_edge, b_edge, outp);
}

// Round 3
// 132.930 us; speedup vs baseline: 1.4046x; 1.4046x over previous
//
#include <hip/hip_runtime.h>
#include <hip/hip_bf16.h>

// out[i] = sum_{j!=i} relu(Wd_i@x_j + (Ws_i-Wd_i)@x_i + b_i) * x_j + x_i, 3 steps.
// MFMA 16x16x32 f16 with SCALED 2-WAY f16 split: v = h + m*2^-11 (rep err
// ~2^-24, fp32-class: absmax 1.0 == fp32 baseline R1/R7).
// Edge: hh + 2^-11*(hm+mh); Q keeps mm too.
// R8: 512-thread blocks, 8 waves, wave w = receiver w (ONE receiver/wave).
// R9 (=R8 rerun): 64.5us, VGPR=48, Occ 36%, Mfma 28%, VALU 43%, BANK_CONFLICT
//   8.55M (~22% of cycles) + LDS pipe ~54% busy -> LDS is the hot pipe.
// R10 FAILED: (512,8) -> spills (FETCH 186MB). True reg need is 85..128/wave;
//   occupancy not buyable via launch bounds. Reverted to (512,4).
// R11: FRAGMENT-MAJOR LDS. Store B-frags/gate values keyed by the consuming
//   lane: xsf[split][n][lane][8 f16], xgf[n][tile][lane][4 f32]. Every hot
//   read (Q, sender bh/bm, gate xgj) and the step xg-write become
//   addr = base + lane*16B -> canonical linear b128, conflict-free.
//   Epilogue staging deleted: fragments store direct (64B segments/quad).
//   LDS 38912 -> 32768 B.
// Spill go/no-go: FETCH/WRITE must stay ~37/37 MB (R4/R6/R10 spills: 166-270).

#define NN 8
#define NSTEPS 3
#define BB 4
#define CC 32
#define HWSZ 9216
#define PX 16
#define MSC 2048.0f
#define SINV 4.8828125e-4f   // 2^-11

typedef _Float16 f16x8 __attribute__((ext_vector_type(8)));
typedef _Float16 f16x4 __attribute__((ext_vector_type(4)));
typedef _Float16 f16x2 __attribute__((ext_vector_type(2)));
typedef float    f32x4 __attribute__((ext_vector_type(4)));
typedef float    f32x2 __attribute__((ext_vector_type(2)));

#define MFMA(A, B, C) __builtin_amdgcn_mfma_f32_16x16x32_f16((A), (B), (C), 0, 0, 0)

__device__ __forceinline__ void split2s(float v, _Float16& h, _Float16& m) {
    h = (_Float16)v;
    m = (_Float16)((v - (float)h) * MSC);
}

__global__ __launch_bounds__(512, 4)
void gcn3_f16w(const float* __restrict__ nodes,
               const float* __restrict__ we,
               const float* __restrict__ be,
               float* __restrict__ out) {
    // Fragment-major: slot [lane] holds exactly the 16B that lane consumes.
    // xsf[s][n][lane][e]: B-frag f16 pair; lane = (c>>3)*16 + pixel, e = c&7.
    // xgf[n][t][lane][k]: fp32 gate master; lane = ((c>>2)&3)*16 + pixel, k = c&3, t = c>>4.
    __shared__ _Float16 xsf[2][NN][64][8];   // 16384 B
    __shared__ float    xgf[NN][2][64][4];   // 16384 B (total 32768)

    const int tid  = threadIdx.x;
    const int wid  = tid >> 6;     // receiver node i (0..7), one per wave
    const int lane = tid & 63;
    const int col  = lane & 15;    // pixel (B n / C col); A row m
    const int quad = lane >> 4;    // 0..3

    const f32x4 zero4 = {0.f, 0.f, 0.f, 0.f};

    // ---- resident A-frags for ONE receiver: Wd, (Ws-Wd); 2-way scaled split ----
    f16x8 awd[2][2], awsd[2][2];   // [tile][split] = 32 VGPRs
    f32x4 bias[2];
    #pragma unroll
    for (int t = 0; t < 2; ++t) {
        const float* wp = we + (size_t)((wid * CC + 16 * t + col) * (2 * CC)) + quad * 8;
        f32x4 d0 = *(const f32x4*)wp;
        f32x4 d1 = *(const f32x4*)(wp + 4);
        f32x4 s0 = *(const f32x4*)(wp + CC);
        f32x4 s1 = *(const f32x4*)(wp + CC + 4);
        #pragma unroll
        for (int k = 0; k < 8; ++k) {
            float d = (k < 4) ? d0[k & 3] : d1[k & 3];
            float s = (k < 4) ? s0[k & 3] : s1[k & 3];
            _Float16 h, m;
            split2s(d, h, m);
            awd[t][0][k] = h; awd[t][1][k] = m;
            split2s(s - d, h, m);
            awsd[t][0][k] = h; awsd[t][1][k] = m;
        }
        #pragma unroll
        for (int k = 0; k < 4; ++k)
            bias[t][k] = be[wid * CC + 16 * t + quad * 4 + k];
    }

    const int q0  = blockIdx.x * PX;
    const int b   = q0 / HWSZ;
    const int hw0 = q0 - b * HWSZ;

    // ---- stage: 1024 f32x2 units over 512 threads (2 iters) ----
    #pragma unroll
    for (int kk = 0; kk < 2; ++kk) {
        int idx = tid + kk * 512;            // 1024 = 8n * 16c2 * 8p2
        int p2 = (idx & 7) * 2;
        int c2 = ((idx >> 3) & 15) * 2;
        int n  = idx >> 7;
        const float* gp = nodes + (size_t)((n * BB + b) * CC + c2) * HWSZ + hw0 + p2;
        f32x2 v0 = *(const f32x2*)gp;            // channel c2
        f32x2 v1 = *(const f32x2*)(gp + HWSZ);   // channel c2+1
        #pragma unroll
        for (int e = 0; e < 2; ++e) {
            int px = p2 + e;
            _Float16 h0, m0, h1, m1;
            split2s(v0[e], h0, m0);
            split2s(v1[e], h1, m1);
            // channels c2, c2+1 are adjacent elems of the same B-frag slot
            *(f16x2*)&xsf[0][n][(c2 >> 3) * 16 + px][c2 & 7] = f16x2{h0, h1};
            *(f16x2*)&xsf[1][n][(c2 >> 3) * 16 + px][c2 & 7] = f16x2{m0, m1};
            *(f32x2*)&xgf[n][c2 >> 4][((c2 >> 2) & 3) * 16 + px][c2 & 3] = f32x2{v0[e], v1[e]};
        }
    }
    __syncthreads();

    f32x4 msg[2];

    #pragma unroll 1
    for (int step = 0; step < NSTEPS; ++step) {
        // ---- Q = (Ws-Wd)_i @ x_i + b : all 4 split products ----
        f32x4 qf[2];
        {
            f16x8 bh = *(const f16x8*)&xsf[0][wid][lane][0];
            f16x8 bm = *(const f16x8*)&xsf[1][wid][lane][0];
            #pragma unroll
            for (int t = 0; t < 2; ++t) {
                f32x4 q1 = MFMA(awsd[t][0], bh, bias[t]);   // hh (+bias)
                f32x4 q2 = MFMA(awsd[t][0], bm, zero4);     // hm
                q2 = MFMA(awsd[t][1], bh, q2);              // mh
                f32x4 q3 = MFMA(awsd[t][1], bm, zero4);     // mm
                #pragma unroll
                for (int k = 0; k < 4; ++k)
                    qf[t][k] = fmaf(fmaf(q3[k], SINV, q2[k]), SINV, q1[k]);
            }
        }

        #pragma unroll
        for (int t = 0; t < 2; ++t)
            msg[t] = zero4;

        // ---- sender loop: E = Wd x_j + Q (hh, hm, mh kept) ----
        #pragma unroll
        for (int j = 0; j < NN; ++j) {
            f32x4 xgj[2];
            #pragma unroll
            for (int t = 0; t < 2; ++t)
                xgj[t] = *(const f32x4*)&xgf[j][t][lane][0];
            if (j == wid) {                  // wave-uniform: residual
                #pragma unroll
                for (int t = 0; t < 2; ++t)
                    #pragma unroll
                    for (int k = 0; k < 4; ++k)
                        msg[t][k] += xgj[t][k];
            } else {
                f16x8 bh = *(const f16x8*)&xsf[0][j][lane][0];
                f16x8 bm = *(const f16x8*)&xsf[1][j][lane][0];
                #pragma unroll
                for (int t = 0; t < 2; ++t) {
                    f32x4 e1 = MFMA(awd[t][0], bh, qf[t]);   // hh (+Q)
                    f32x4 e2 = MFMA(awd[t][0], bm, zero4);   // hm
                    e2 = MFMA(awd[t][1], bh, e2);            // mh
                    #pragma unroll
                    for (int k = 0; k < 4; ++k) {
                        float g = fmaxf(fmaf(e2[k], SINV, e1[k]), 0.f);
                        msg[t][k] = fmaf(g, xgj[t][k], msg[t][k]);
                    }
                }
            }
        }

        if (step < NSTEPS - 1) {
            __syncthreads();   // all reads of old x done
            #pragma unroll
            for (int t = 0; t < 2; ++t) {
                f16x4 h4, m4;
                #pragma unroll
                for (int k = 0; k < 4; ++k) {
                    _Float16 h, m;
                    split2s(msg[t][k], h, m);
                    h4[k] = h; m4[k] = m;
                }
                // channel c = 16t + quad*4 + k  ->  xsf slot (c>>3)*16+col, elem c&7
                int lane2 = (2 * t + (quad >> 1)) * 16 + col;
                int e0    = (quad & 1) * 4;
                *(f16x4*)&xsf[0][wid][lane2][e0] = h4;
                *(f16x4*)&xsf[1][wid][lane2][e0] = m4;
                *(f32x4*)&xgf[wid][t][lane][0] = msg[t];   // linear: conflict-free
            }
            __syncthreads();   // new x visible
        }
    }

    // ---- epilogue: direct fragment stores (per (t,k): 16-lane x 4B = 64B segs) ----
    #pragma unroll
    for (int t = 0; t < 2; ++t)
        #pragma unroll
        for (int k = 0; k < 4; ++k)
            out[(size_t)((wid * BB + b) * CC + 16 * t + quad * 4 + k) * HWSZ + hw0 + col] = msg[t][k];
}

extern "C" void kernel_launch(void* const* d_in, const int* in_sizes, int n_in,
                              void* d_out, int out_size, void* d_ws, size_t ws_size,
                              hipStream_t stream) {
    const float* nodes  = (const float*)d_in[0];
    const float* W_edge = (const float*)d_in[1];
    const float* b_edge = (const float*)d_in[2];
    float* outp = (float*)d_out;

    dim3 grid((BB * HWSZ) / PX);   // 2304 blocks of 512
    dim3 block(512);
    gcn3_f16w<<<grid, block, 0, stream>>>(nodes, W_edge, b_edge, outp);
}